// Round 1
// baseline (36.960 us; speedup 1.0000x reference)
//
#include <hip/hip_runtime.h>

// Problem constants (from reference setup_inputs): B=64, S=2048, Q=512.
constexpr int B_ = 64;
constexpr int S_ = 2048;
constexpr int Q_ = 512;

// Fast tanh: tanh(x) = 1 - 2/(exp(2x)+1).  v_exp_f32 + v_rcp_f32, ~1e-6 rel err.
// Saturates correctly: x>>0 -> exp=inf -> rcp=0 -> 1; x<<0 -> exp=0 -> -1.
__device__ __forceinline__ float tanh_fast(float x) {
  float e = __expf(2.0f * x);
  float r = __builtin_amdgcn_rcpf(e + 1.0f);
  return fmaf(-2.0f, r, 1.0f);
}

__device__ __forceinline__ float wave_reduce_sum(float v) {
#pragma unroll
  for (int off = 32; off > 0; off >>= 1) v += __shfl_xor(v, off, 64);
  return v;
}

// ---------------------------------------------------------------------------
// Kernel 1: pq[b*Q+d] = sum_q query[b*Q+q] * Wq[d*Q+q]
// One wave per output element; lane i covers q = 4i..4i+3 and 256+4i..256+4i+3.
// ---------------------------------------------------------------------------
__global__ __launch_bounds__(256) void proj_kernel(const float* __restrict__ query,
                                                   const float* __restrict__ Wq,
                                                   float* __restrict__ pq) {
  int wave = threadIdx.x >> 6, lane = threadIdx.x & 63;
  int out = blockIdx.x * 4 + wave;  // [0, B*Q)
  int b = out >> 9;                 // Q = 512
  int d = out & (Q_ - 1);
  int q0 = lane * 4, q1 = 256 + lane * 4;
  float4 qa = *(const float4*)(query + b * Q_ + q0);
  float4 qb = *(const float4*)(query + b * Q_ + q1);
  float4 wa = *(const float4*)(Wq + (long long)d * Q_ + q0);
  float4 wb = *(const float4*)(Wq + (long long)d * Q_ + q1);
  float acc = qa.x * wa.x + qa.y * wa.y + qa.z * wa.z + qa.w * wa.w +
              qb.x * wb.x + qb.y * wb.y + qb.z * wb.z + qb.w * wb.w;
  acc = wave_reduce_sum(acc);
  if (lane == 0) pq[out] = acc;
}

// ---------------------------------------------------------------------------
// Kernel 2: energy[b,s] = mask ? sum_q We[q]*tanh(pq[b,q]+pm[b,s,q]) : -1000
// One wave per (b,s) row, 8 rows per wave (same b), mask-skip avoids the
// 2 KB pm row read entirely for masked rows (~50% of traffic).
// ---------------------------------------------------------------------------
__global__ __launch_bounds__(256) void energy_kernel(const float* __restrict__ pm,
                                                     const int* __restrict__ mask,
                                                     const float* __restrict__ pq,
                                                     const float* __restrict__ We,
                                                     float* __restrict__ energy) {
  int wave = threadIdx.x >> 6, lane = threadIdx.x & 63;
  int w = blockIdx.x * 4 + wave;  // wave id in [0, B*S/8)
  int b = w >> 8;                 // 2048/8 = 256 waves per b
  int s0 = (w & 255) * 8;
  int q0 = lane * 4, q1 = 256 + lane * 4;

  const float* pqrow = pq + b * Q_;
  float4 pa = *(const float4*)(pqrow + q0);
  float4 pb = *(const float4*)(pqrow + q1);
  float4 wa = *(const float4*)(We + q0);
  float4 wb = *(const float4*)(We + q1);

  const float* pmb = pm + ((long long)b * S_ + s0) * Q_;
  const int* mrow = mask + b * S_ + s0;
  float* erow = energy + b * S_ + s0;

#pragma unroll
  for (int r = 0; r < 8; ++r) {
    if (mrow[r] == 0) {  // wave-uniform branch: skip the whole 2 KB row
      if (lane == 0) erow[r] = -1000.0f;
      continue;
    }
    const float* prow = pmb + (long long)r * Q_;
    float4 ma = *(const float4*)(prow + q0);
    float4 mb = *(const float4*)(prow + q1);
    float acc = wa.x * tanh_fast(pa.x + ma.x);
    acc = fmaf(wa.y, tanh_fast(pa.y + ma.y), acc);
    acc = fmaf(wa.z, tanh_fast(pa.z + ma.z), acc);
    acc = fmaf(wa.w, tanh_fast(pa.w + ma.w), acc);
    acc = fmaf(wb.x, tanh_fast(pb.x + mb.x), acc);
    acc = fmaf(wb.y, tanh_fast(pb.y + mb.y), acc);
    acc = fmaf(wb.z, tanh_fast(pb.z + mb.z), acc);
    acc = fmaf(wb.w, tanh_fast(pb.w + mb.w), acc);
    acc = wave_reduce_sum(acc);
    if (lane == 0) erow[r] = acc;
  }
}

// ---------------------------------------------------------------------------
// Kernel 3: in-place softmax over S per b. One block per b, 256 threads,
// 8 values per thread (2x float4). Values first read to registers, so the
// in-place write-back is race-free within the owning block.
// ---------------------------------------------------------------------------
__global__ __launch_bounds__(256) void softmax_kernel(float* __restrict__ e) {
  int b = blockIdx.x, t = threadIdx.x;
  float* row = e + b * S_;
  float4 v0 = *(const float4*)(row + 4 * t);
  float4 v1 = *(const float4*)(row + 1024 + 4 * t);

  __shared__ float redmax[4];
  __shared__ float redsum[4];

  float mx = fmaxf(fmaxf(fmaxf(v0.x, v0.y), fmaxf(v0.z, v0.w)),
                   fmaxf(fmaxf(v1.x, v1.y), fmaxf(v1.z, v1.w)));
#pragma unroll
  for (int off = 32; off > 0; off >>= 1) mx = fmaxf(mx, __shfl_xor(mx, off, 64));
  if ((t & 63) == 0) redmax[t >> 6] = mx;
  __syncthreads();
  mx = fmaxf(fmaxf(redmax[0], redmax[1]), fmaxf(redmax[2], redmax[3]));

  float e0 = __expf(v0.x - mx), e1 = __expf(v0.y - mx);
  float e2 = __expf(v0.z - mx), e3 = __expf(v0.w - mx);
  float e4 = __expf(v1.x - mx), e5 = __expf(v1.y - mx);
  float e6 = __expf(v1.z - mx), e7 = __expf(v1.w - mx);

  float sum = ((e0 + e1) + (e2 + e3)) + ((e4 + e5) + (e6 + e7));
  sum = wave_reduce_sum(sum);
  if ((t & 63) == 0) redsum[t >> 6] = sum;
  __syncthreads();
  sum = (redsum[0] + redsum[1]) + (redsum[2] + redsum[3]);

  float inv = 1.0f / sum;
  float4 o0 = {e0 * inv, e1 * inv, e2 * inv, e3 * inv};
  float4 o1 = {e4 * inv, e5 * inv, e6 * inv, e7 * inv};
  *(float4*)(row + 4 * t) = o0;
  *(float4*)(row + 1024 + 4 * t) = o1;
}

// ---------------------------------------------------------------------------
extern "C" void kernel_launch(void* const* d_in, const int* in_sizes, int n_in,
                              void* d_out, int out_size, void* d_ws, size_t ws_size,
                              hipStream_t stream) {
  const float* query = (const float*)d_in[0];  // [1,B,Q]
  const float* pm    = (const float*)d_in[1];  // [B,S,Q]
  const int*   mask  = (const int*)d_in[2];    // [B,S]
  const float* Wq    = (const float*)d_in[3];  // [Q,Q]
  const float* We    = (const float*)d_in[4];  // [Q]
  float* out = (float*)d_out;                  // [B,1,S] -> energies then attn
  float* pq  = (float*)d_ws;                   // B*Q floats = 128 KB scratch

  // 1) projection: B*Q = 32768 outputs, 4 waves/block -> 8192 blocks
  proj_kernel<<<8192, 256, 0, stream>>>(query, Wq, pq);
  // 2) energy: B*S/8 = 16384 waves, 4 waves/block -> 4096 blocks
  energy_kernel<<<4096, 256, 0, stream>>>(pm, mask, pq, We, out);
  // 3) softmax: one block per b
  softmax_kernel<<<B_, 256, 0, stream>>>(out);
}